// Round 2
// baseline (674.505 us; speedup 1.0000x reference)
//
#include <hip/hip_runtime.h>

#define C_CH 128
#define G_SEGS 1024

typedef float v4f __attribute__((ext_vector_type(4)));

__device__ __forceinline__ v4f fma4(v4f a, float s, v4f c) {
    c.x = fmaf(a.x, s, c.x);
    c.y = fmaf(a.y, s, c.y);
    c.z = fmaf(a.z, s, c.z);
    c.w = fmaf(a.w, s, c.w);
    return c;
}

__device__ __forceinline__ void flush_acc(float* __restrict__ U, int seg, int col4,
                                          v4f& acc) {
    float* dst = U + (size_t)seg * C_CH + col4 * 4;
    atomicAdd(dst + 0, acc.x);
    atomicAdd(dst + 1, acc.y);
    atomicAdd(dst + 2, acc.z);
    atomicAdd(dst + 3, acc.w);
    acc = (v4f){0.f, 0.f, 0.f, 0.f};
}

// 16 rows per wave iteration, 8x 1KB loads (8KB contiguous).
// R1 = R0 resubmit (R0 bench was an infra failure, experiment unmeasured).
// Experiment: x loads are PLAIN (cached) instead of nontemporal.
// Theory: nt-bit streaming policy caps effective read BW (~1.7 TB/s observed
// by subtraction); everything else (VALU/DS/atomic budgets) sits far below
// HBM pace. Single-variable change; all else identical to the 648us kernel.
__global__ __launch_bounds__(256) void nap_main(
    const float* __restrict__ x, const float* __restrict__ W,
    const float* __restrict__ b, const int* __restrict__ batch,
    float* __restrict__ U, float* __restrict__ Z,
    float* __restrict__ e_out, int N)
{
    __shared__ float zred[4];
    const int lane = threadIdx.x & 63;
    const int wid  = threadIdx.x >> 6;
    const int wave = (blockIdx.x * blockDim.x + threadIdx.x) >> 6;
    const int nwaves = (gridDim.x * blockDim.x) >> 6;
    int chunk = (N + nwaves - 1) / nwaves;
    chunk = (chunk + 15) & ~15;               // multiple of 16 rows per wave
    const int row0 = min(N, wave * chunk);
    const int row1 = min(N, row0 + chunk);

    const int col4 = lane & 31;               // which float4 of a row this lane owns
    const int h    = lane >> 5;               // row-parity half
    const v4f w4 = ((const v4f*)W)[col4];
    const float bv = b[0];
    const v4f* x4 = (const v4f*)x;

    v4f acc = {0.f, 0.f, 0.f, 0.f};
    float zloc = 0.f;
    int cur = -1;

    const int ng = (row1 - row0) >> 4;        // 16-row groups

    for (int g = 0; g < ng; ++g) {
        const int rb = row0 + g * 16;
        const v4f* p = x4 + (size_t)rb * (C_CH / 4);
        const v4f a0 = p[lane];               // rows 0,1
        const v4f a1 = p[64  + lane];         // rows 2,3
        const v4f a2 = p[128 + lane];         // rows 4,5
        const v4f a3 = p[192 + lane];         // rows 6,7
        const v4f b0 = p[256 + lane];         // rows 8,9
        const v4f b1 = p[320 + lane];         // rows 10,11
        const v4f b2 = p[384 + lane];         // rows 12,13
        const v4f b3 = p[448 + lane];         // rows 14,15
        const int rbu = __builtin_amdgcn_readfirstlane(rb);
        const int bf = batch[rbu];            // wave-uniform -> s_load
        const int bl = batch[rbu + 15];

        float d0 = fmaf(a0.x, w4.x, fmaf(a0.y, w4.y, fmaf(a0.z, w4.z, a0.w * w4.w)));
        float d1 = fmaf(a1.x, w4.x, fmaf(a1.y, w4.y, fmaf(a1.z, w4.z, a1.w * w4.w)));
        float d2 = fmaf(a2.x, w4.x, fmaf(a2.y, w4.y, fmaf(a2.z, w4.z, a2.w * w4.w)));
        float d3 = fmaf(a3.x, w4.x, fmaf(a3.y, w4.y, fmaf(a3.z, w4.z, a3.w * w4.w)));
        float d4 = fmaf(b0.x, w4.x, fmaf(b0.y, w4.y, fmaf(b0.z, w4.z, b0.w * w4.w)));
        float d5 = fmaf(b1.x, w4.x, fmaf(b1.y, w4.y, fmaf(b1.z, w4.z, b1.w * w4.w)));
        float d6 = fmaf(b2.x, w4.x, fmaf(b2.y, w4.y, fmaf(b2.z, w4.z, b2.w * w4.w)));
        float d7 = fmaf(b3.x, w4.x, fmaf(b3.y, w4.y, fmaf(b3.z, w4.z, b3.w * w4.w)));
        #pragma unroll
        for (int m = 1; m <= 16; m <<= 1) {   // 8 chains interleaved, halves only
            d0 += __shfl_xor(d0, m);
            d1 += __shfl_xor(d1, m);
            d2 += __shfl_xor(d2, m);
            d3 += __shfl_xor(d3, m);
            d4 += __shfl_xor(d4, m);
            d5 += __shfl_xor(d5, m);
            d6 += __shfl_xor(d6, m);
            d7 += __shfl_xor(d7, m);
        }
        const float e0 = __expf(d0 + bv);
        const float e1 = __expf(d1 + bv);
        const float e2 = __expf(d2 + bv);
        const float e3 = __expf(d3 + bv);
        const float e4 = __expf(d4 + bv);
        const float e5 = __expf(d5 + bv);
        const float e6 = __expf(d6 + bv);
        const float e7 = __expf(d7 + bv);

        if (bf == bl) {                       // uniform fast path: one segment
            if (bf != cur) {
                if (cur >= 0) flush_acc(U, cur, col4, acc);
                cur = bf;
            }
            acc.x += e0*a0.x + e1*a1.x + e2*a2.x + e3*a3.x
                   + e4*b0.x + e5*b1.x + e6*b2.x + e7*b3.x;
            acc.y += e0*a0.y + e1*a1.y + e2*a2.y + e3*a3.y
                   + e4*b0.y + e5*b1.y + e6*b2.y + e7*b3.y;
            acc.z += e0*a0.z + e1*a1.z + e2*a2.z + e3*a3.z
                   + e4*b0.z + e5*b1.z + e6*b2.z + e7*b3.z;
            acc.w += e0*a0.w + e1*a1.w + e2*a2.w + e3*a3.w
                   + e4*b0.w + e5*b1.w + e6*b2.w + e7*b3.w;
        } else {                              // rare: boundary inside the group
            const int r = rb + h;             // this half's rows: r, r+2, ..., r+14
            const int s0 = batch[r];
            const int s1 = batch[r + 2];
            const int s2 = batch[r + 4];
            const int s3 = batch[r + 6];
            const int s4 = batch[r + 8];
            const int s5 = batch[r + 10];
            const int s6 = batch[r + 12];
            const int s7 = batch[r + 14];
            if (s0 != cur) { if (cur >= 0) flush_acc(U, cur, col4, acc); cur = s0; }
            acc = fma4(a0, e0, acc);
            if (s1 != cur) { flush_acc(U, cur, col4, acc); cur = s1; }
            acc = fma4(a1, e1, acc);
            if (s2 != cur) { flush_acc(U, cur, col4, acc); cur = s2; }
            acc = fma4(a2, e2, acc);
            if (s3 != cur) { flush_acc(U, cur, col4, acc); cur = s3; }
            acc = fma4(a3, e3, acc);
            if (s4 != cur) { flush_acc(U, cur, col4, acc); cur = s4; }
            acc = fma4(b0, e4, acc);
            if (s5 != cur) { flush_acc(U, cur, col4, acc); cur = s5; }
            acc = fma4(b1, e5, acc);
            if (s6 != cur) { flush_acc(U, cur, col4, acc); cur = s6; }
            acc = fma4(b2, e6, acc);
            if (s7 != cur) { flush_acc(U, cur, col4, acc); cur = s7; }
            acc = fma4(b3, e7, acc);
        }

        // alpha (unnormalized exp): 16 rows -> four float4 nt stores (2 lanes)
        const float p0 = __shfl_xor(e0, 32);
        const float p1 = __shfl_xor(e1, 32);
        const float p2 = __shfl_xor(e2, 32);
        const float p3 = __shfl_xor(e3, 32);
        const float p4 = __shfl_xor(e4, 32);
        const float p5 = __shfl_xor(e5, 32);
        const float p6 = __shfl_xor(e6, 32);
        const float p7 = __shfl_xor(e7, 32);
        if (lane == 0) {
            v4f u0 = {e0, p0, e1, p1};        // rows 0..3
            v4f u1 = {e4, p4, e5, p5};        // rows 8..11
            __builtin_nontemporal_store(u0, (v4f*)(e_out + rb));
            __builtin_nontemporal_store(u1, (v4f*)(e_out + rb + 8));
            zloc += e0 + e1 + e2 + e3 + e4 + e5 + e6 + e7;   // even rows
        } else if (lane == 32) {
            v4f u0 = {p2, e2, p3, e3};        // rows 4..7
            v4f u1 = {p6, e6, p7, e7};        // rows 12..15
            __builtin_nontemporal_store(u0, (v4f*)(e_out + rb + 4));
            __builtin_nontemporal_store(u1, (v4f*)(e_out + rb + 12));
            zloc += e0 + e1 + e2 + e3 + e4 + e5 + e6 + e7;   // odd rows
        }
    }

    // generic scalar tail (unused when chunk divides cleanly; kept for safety)
    for (int rb = row0 + ng * 16; rb < row1; ++rb) {
        const v4f xv = x4[(size_t)rb * (C_CH / 4) + col4];
        float d = fmaf(xv.x, w4.x, fmaf(xv.y, w4.y, fmaf(xv.z, w4.z, xv.w * w4.w)));
        #pragma unroll
        for (int m = 1; m <= 16; m <<= 1) d += __shfl_xor(d, m);
        const float e = __expf(d + bv);
        const int s = batch[rb];
        if (h == 0) {
            if (s != cur) { if (cur >= 0) flush_acc(U, cur, col4, acc); cur = s; }
            acc = fma4(xv, e, acc);
            if (lane == 0) { e_out[rb] = e; zloc += e; }
        }
    }

    if (cur >= 0) flush_acc(U, cur, col4, acc);

    // Z: wave -> block -> one atomic per block
    zloc += __shfl_xor(zloc, 32);
    if (lane == 0) zred[wid] = zloc;
    __syncthreads();
    if (threadIdx.x == 0)
        atomicAdd(Z, zred[0] + zred[1] + zred[2] + zred[3]);
}

__global__ __launch_bounds__(256) void nap_finalize(
    const float* __restrict__ U, const float* __restrict__ Z,
    float* __restrict__ pooled, float* __restrict__ alpha,
    int gc, int n)
{
    const float inv = 1.0f / (*Z);
    const int tid = blockIdx.x * blockDim.x + threadIdx.x;
    const int stride = gridDim.x * blockDim.x;
    const int gc4 = gc >> 2;
    const int n4 = n >> 2;
    for (int k = tid; k < gc4; k += stride) {
        v4f u = ((const v4f*)U)[k];
        u.x *= inv; u.y *= inv; u.z *= inv; u.w *= inv;
        __builtin_nontemporal_store(u, (v4f*)pooled + k);
    }
    for (int k = tid; k < n4; k += stride) {
        v4f e = ((const v4f*)alpha)[k];
        e.x *= inv; e.y *= inv; e.z *= inv; e.w *= inv;
        __builtin_nontemporal_store(e, (v4f*)alpha + k);
    }
    for (int k = gc4 * 4 + tid; k < gc; k += stride) pooled[k] = U[k] * inv;
    for (int k = n4 * 4 + tid; k < n; k += stride) alpha[k] = alpha[k] * inv;
}

extern "C" void kernel_launch(void* const* d_in, const int* in_sizes, int n_in,
                              void* d_out, int out_size, void* d_ws, size_t ws_size,
                              hipStream_t stream) {
    const float* x     = (const float*)d_in[0];
    const float* W     = (const float*)d_in[1];
    const float* b     = (const float*)d_in[2];
    const int*   batch = (const int*)d_in[3];
    const int N = in_sizes[3];

    float* U = (float*)d_ws;                  // [G_SEGS * C_CH] unnormalized sums
    float* Z = U + (size_t)G_SEGS * C_CH;     // [1] global sum of exp
    float* pooled = (float*)d_out;                    // [G_SEGS * C_CH]
    float* alpha  = pooled + (size_t)G_SEGS * C_CH;   // [N]

    hipMemsetAsync(d_ws, 0, ((size_t)G_SEGS * C_CH + 1) * sizeof(float), stream);

    // 1536 blocks = 6144 waves: co-resident in one dispatch pass at >=6
    // waves/SIMD, so every wave starts at t=0 (no dispatch tail).
    nap_main<<<1536, 256, 0, stream>>>(x, W, b, batch, U, Z, alpha, N);
    nap_finalize<<<512, 256, 0, stream>>>(U, Z, pooled, alpha, G_SEGS * C_CH, N);
}

// Round 4
// 653.403 us; speedup vs baseline: 1.0323x; 1.0323x over previous
//
#include <hip/hip_runtime.h>

#define C_CH 128
#define G_SEGS 1024

typedef float v4f __attribute__((ext_vector_type(4)));

// DPP controls (gfx9/CDNA): quad_perm via perm bytes, row mirrors
#define DPP_XOR1  0xB1   // quad_perm [1,0,3,2]
#define DPP_XOR2  0x4E   // quad_perm [2,3,0,1]
#define DPP_HMIRR 0x141  // row_half_mirror (i^7) == xor4 after xor1,xor2
#define DPP_MIRR  0x140  // row_mirror     (i^15) == xor8 after xor1,2,4

template <int CTRL>
__device__ __forceinline__ float dpp_xadd(float x) {
    int t = __builtin_amdgcn_update_dpp(0, __float_as_int(x), CTRL, 0xf, 0xf, true);
    return x + __int_as_float(t);
}

#define DPP_STEP(CTRL)            \
    d0 = dpp_xadd<CTRL>(d0);      \
    d1 = dpp_xadd<CTRL>(d1);      \
    d2 = dpp_xadd<CTRL>(d2);      \
    d3 = dpp_xadd<CTRL>(d3);      \
    d4 = dpp_xadd<CTRL>(d4);      \
    d5 = dpp_xadd<CTRL>(d5);      \
    d6 = dpp_xadd<CTRL>(d6);      \
    d7 = dpp_xadd<CTRL>(d7);

__device__ __forceinline__ v4f fma4(v4f a, float s, v4f c) {
    c.x = fmaf(a.x, s, c.x);
    c.y = fmaf(a.y, s, c.y);
    c.z = fmaf(a.z, s, c.z);
    c.w = fmaf(a.w, s, c.w);
    return c;
}

__device__ __forceinline__ void flush_acc(float* __restrict__ U, int seg, int col4,
                                          v4f& acc) {
    float* dst = U + (size_t)seg * C_CH + col4 * 4;
    atomicAdd(dst + 0, acc.x);
    atomicAdd(dst + 1, acc.y);
    atomicAdd(dst + 2, acc.z);
    atomicAdd(dst + 3, acc.w);
    acc = (v4f){0.f, 0.f, 0.f, 0.f};
}

// R4 = R3 with the DPP ctrl as a template parameter (builtin requires a
// constant-int at the call site; runtime param failed to compile).
// (1) 32-lane allreduce: 4x VALU DPP adds + 1 shfl_xor(16). DS ops/group
// 48 -> 16; dependency chain mostly back-to-back VALU instead of ~30cy DS
// round-trips. (2) 1024 blocks + __launch_bounds__(256,4): 4 blocks/CU
// guaranteed co-resident (VGPR cap 128), chunk = 256 rows/wave. NT x loads
// (R2: plain loads cost +10% on nap_main).
__global__ __launch_bounds__(256, 4) void nap_main(
    const float* __restrict__ x, const float* __restrict__ W,
    const float* __restrict__ b, const int* __restrict__ batch,
    float* __restrict__ U, float* __restrict__ Z,
    float* __restrict__ e_out, int N)
{
    __shared__ float zred[4];
    const int lane = threadIdx.x & 63;
    const int wid  = threadIdx.x >> 6;
    const int wave = (blockIdx.x * blockDim.x + threadIdx.x) >> 6;
    const int nwaves = (gridDim.x * blockDim.x) >> 6;
    int chunk = (N + nwaves - 1) / nwaves;
    chunk = (chunk + 15) & ~15;               // multiple of 16 rows per wave
    const int row0 = min(N, wave * chunk);
    const int row1 = min(N, row0 + chunk);

    const int col4 = lane & 31;               // which float4 of a row this lane owns
    const int h    = lane >> 5;               // row-parity half
    const v4f w4 = ((const v4f*)W)[col4];
    const float bv = b[0];
    const v4f* x4 = (const v4f*)x;

    v4f acc = {0.f, 0.f, 0.f, 0.f};
    float zloc = 0.f;
    int cur = -1;

    const int ng = (row1 - row0) >> 4;        // 16-row groups

    for (int g = 0; g < ng; ++g) {
        const int rb = row0 + g * 16;
        const v4f* p = x4 + (size_t)rb * (C_CH / 4);
        const v4f a0 = __builtin_nontemporal_load(p + lane);         // rows 0,1
        const v4f a1 = __builtin_nontemporal_load(p + 64  + lane);   // rows 2,3
        const v4f a2 = __builtin_nontemporal_load(p + 128 + lane);   // rows 4,5
        const v4f a3 = __builtin_nontemporal_load(p + 192 + lane);   // rows 6,7
        const v4f b0 = __builtin_nontemporal_load(p + 256 + lane);   // rows 8,9
        const v4f b1 = __builtin_nontemporal_load(p + 320 + lane);   // rows 10,11
        const v4f b2 = __builtin_nontemporal_load(p + 384 + lane);   // rows 12,13
        const v4f b3 = __builtin_nontemporal_load(p + 448 + lane);   // rows 14,15
        const int rbu = __builtin_amdgcn_readfirstlane(rb);
        const int bf = batch[rbu];            // wave-uniform -> s_load
        const int bl = batch[rbu + 15];

        float d0 = fmaf(a0.x, w4.x, fmaf(a0.y, w4.y, fmaf(a0.z, w4.z, a0.w * w4.w)));
        float d1 = fmaf(a1.x, w4.x, fmaf(a1.y, w4.y, fmaf(a1.z, w4.z, a1.w * w4.w)));
        float d2 = fmaf(a2.x, w4.x, fmaf(a2.y, w4.y, fmaf(a2.z, w4.z, a2.w * w4.w)));
        float d3 = fmaf(a3.x, w4.x, fmaf(a3.y, w4.y, fmaf(a3.z, w4.z, a3.w * w4.w)));
        float d4 = fmaf(b0.x, w4.x, fmaf(b0.y, w4.y, fmaf(b0.z, w4.z, b0.w * w4.w)));
        float d5 = fmaf(b1.x, w4.x, fmaf(b1.y, w4.y, fmaf(b1.z, w4.z, b1.w * w4.w)));
        float d6 = fmaf(b2.x, w4.x, fmaf(b2.y, w4.y, fmaf(b2.z, w4.z, b2.w * w4.w)));
        float d7 = fmaf(b3.x, w4.x, fmaf(b3.y, w4.y, fmaf(b3.z, w4.z, b3.w * w4.w)));

        // 32-lane allreduce: 4 DPP VALU steps + 1 shuffle (xor16)
        DPP_STEP(DPP_XOR1)
        DPP_STEP(DPP_XOR2)
        DPP_STEP(DPP_HMIRR)
        DPP_STEP(DPP_MIRR)
        d0 += __shfl_xor(d0, 16);
        d1 += __shfl_xor(d1, 16);
        d2 += __shfl_xor(d2, 16);
        d3 += __shfl_xor(d3, 16);
        d4 += __shfl_xor(d4, 16);
        d5 += __shfl_xor(d5, 16);
        d6 += __shfl_xor(d6, 16);
        d7 += __shfl_xor(d7, 16);

        const float e0 = __expf(d0 + bv);
        const float e1 = __expf(d1 + bv);
        const float e2 = __expf(d2 + bv);
        const float e3 = __expf(d3 + bv);
        const float e4 = __expf(d4 + bv);
        const float e5 = __expf(d5 + bv);
        const float e6 = __expf(d6 + bv);
        const float e7 = __expf(d7 + bv);

        if (bf == bl) {                       // uniform fast path: one segment
            if (bf != cur) {
                if (cur >= 0) flush_acc(U, cur, col4, acc);
                cur = bf;
            }
            acc.x += e0*a0.x + e1*a1.x + e2*a2.x + e3*a3.x
                   + e4*b0.x + e5*b1.x + e6*b2.x + e7*b3.x;
            acc.y += e0*a0.y + e1*a1.y + e2*a2.y + e3*a3.y
                   + e4*b0.y + e5*b1.y + e6*b2.y + e7*b3.y;
            acc.z += e0*a0.z + e1*a1.z + e2*a2.z + e3*a3.z
                   + e4*b0.z + e5*b1.z + e6*b2.z + e7*b3.z;
            acc.w += e0*a0.w + e1*a1.w + e2*a2.w + e3*a3.w
                   + e4*b0.w + e5*b1.w + e6*b2.w + e7*b3.w;
        } else {                              // rare: boundary inside the group
            const int r = rb + h;             // this half's rows: r, r+2, ..., r+14
            const int s0 = batch[r];
            const int s1 = batch[r + 2];
            const int s2 = batch[r + 4];
            const int s3 = batch[r + 6];
            const int s4 = batch[r + 8];
            const int s5 = batch[r + 10];
            const int s6 = batch[r + 12];
            const int s7 = batch[r + 14];
            if (s0 != cur) { if (cur >= 0) flush_acc(U, cur, col4, acc); cur = s0; }
            acc = fma4(a0, e0, acc);
            if (s1 != cur) { flush_acc(U, cur, col4, acc); cur = s1; }
            acc = fma4(a1, e1, acc);
            if (s2 != cur) { flush_acc(U, cur, col4, acc); cur = s2; }
            acc = fma4(a2, e2, acc);
            if (s3 != cur) { flush_acc(U, cur, col4, acc); cur = s3; }
            acc = fma4(a3, e3, acc);
            if (s4 != cur) { flush_acc(U, cur, col4, acc); cur = s4; }
            acc = fma4(b0, e4, acc);
            if (s5 != cur) { flush_acc(U, cur, col4, acc); cur = s5; }
            acc = fma4(b1, e5, acc);
            if (s6 != cur) { flush_acc(U, cur, col4, acc); cur = s6; }
            acc = fma4(b2, e6, acc);
            if (s7 != cur) { flush_acc(U, cur, col4, acc); cur = s7; }
            acc = fma4(b3, e7, acc);
        }

        // alpha (unnormalized exp): 16 rows -> four float4 nt stores (2 lanes)
        const float p0 = __shfl_xor(e0, 32);
        const float p1 = __shfl_xor(e1, 32);
        const float p2 = __shfl_xor(e2, 32);
        const float p3 = __shfl_xor(e3, 32);
        const float p4 = __shfl_xor(e4, 32);
        const float p5 = __shfl_xor(e5, 32);
        const float p6 = __shfl_xor(e6, 32);
        const float p7 = __shfl_xor(e7, 32);
        if (lane == 0) {
            v4f u0 = {e0, p0, e1, p1};        // rows 0..3
            v4f u1 = {e4, p4, e5, p5};        // rows 8..11
            __builtin_nontemporal_store(u0, (v4f*)(e_out + rb));
            __builtin_nontemporal_store(u1, (v4f*)(e_out + rb + 8));
            zloc += e0 + e1 + e2 + e3 + e4 + e5 + e6 + e7;   // even rows
        } else if (lane == 32) {
            v4f u0 = {p2, e2, p3, e3};        // rows 4..7
            v4f u1 = {p6, e6, p7, e7};        // rows 12..15
            __builtin_nontemporal_store(u0, (v4f*)(e_out + rb + 4));
            __builtin_nontemporal_store(u1, (v4f*)(e_out + rb + 12));
            zloc += e0 + e1 + e2 + e3 + e4 + e5 + e6 + e7;   // odd rows
        }
    }

    // generic scalar tail (unused when chunk divides cleanly; kept for safety)
    for (int rb = row0 + ng * 16; rb < row1; ++rb) {
        const v4f xv = x4[(size_t)rb * (C_CH / 4) + col4];
        float d = fmaf(xv.x, w4.x, fmaf(xv.y, w4.y, fmaf(xv.z, w4.z, xv.w * w4.w)));
        #pragma unroll
        for (int m = 1; m <= 16; m <<= 1) d += __shfl_xor(d, m);
        const float e = __expf(d + bv);
        const int s = batch[rb];
        if (h == 0) {
            if (s != cur) { if (cur >= 0) flush_acc(U, cur, col4, acc); cur = s; }
            acc = fma4(xv, e, acc);
            if (lane == 0) { e_out[rb] = e; zloc += e; }
        }
    }

    if (cur >= 0) flush_acc(U, cur, col4, acc);

    // Z: wave -> block -> one atomic per block
    zloc += __shfl_xor(zloc, 32);
    if (lane == 0) zred[wid] = zloc;
    __syncthreads();
    if (threadIdx.x == 0)
        atomicAdd(Z, zred[0] + zred[1] + zred[2] + zred[3]);
}

__global__ __launch_bounds__(256) void nap_finalize(
    const float* __restrict__ U, const float* __restrict__ Z,
    float* __restrict__ pooled, float* __restrict__ alpha,
    int gc, int n)
{
    const float inv = 1.0f / (*Z);
    const int tid = blockIdx.x * blockDim.x + threadIdx.x;
    const int stride = gridDim.x * blockDim.x;
    const int gc4 = gc >> 2;
    const int n4 = n >> 2;
    for (int k = tid; k < gc4; k += stride) {
        v4f u = ((const v4f*)U)[k];
        u.x *= inv; u.y *= inv; u.z *= inv; u.w *= inv;
        __builtin_nontemporal_store(u, (v4f*)pooled + k);
    }
    for (int k = tid; k < n4; k += stride) {
        v4f e = ((const v4f*)alpha)[k];
        e.x *= inv; e.y *= inv; e.z *= inv; e.w *= inv;
        __builtin_nontemporal_store(e, (v4f*)alpha + k);
    }
    for (int k = gc4 * 4 + tid; k < gc; k += stride) pooled[k] = U[k] * inv;
    for (int k = n4 * 4 + tid; k < n; k += stride) alpha[k] = alpha[k] * inv;
}

extern "C" void kernel_launch(void* const* d_in, const int* in_sizes, int n_in,
                              void* d_out, int out_size, void* d_ws, size_t ws_size,
                              hipStream_t stream) {
    const float* x     = (const float*)d_in[0];
    const float* W     = (const float*)d_in[1];
    const float* b     = (const float*)d_in[2];
    const int*   batch = (const int*)d_in[3];
    const int N = in_sizes[3];

    float* U = (float*)d_ws;                  // [G_SEGS * C_CH] unnormalized sums
    float* Z = U + (size_t)G_SEGS * C_CH;     // [1] global sum of exp
    float* pooled = (float*)d_out;                    // [G_SEGS * C_CH]
    float* alpha  = pooled + (size_t)G_SEGS * C_CH;   // [N]

    hipMemsetAsync(d_ws, 0, ((size_t)G_SEGS * C_CH + 1) * sizeof(float), stream);

    // 1024 blocks = 4096 waves = 4 blocks/CU: guaranteed co-resident at
    // VGPR<=128 (enforced by __launch_bounds__(256,4)); single dispatch pass.
    nap_main<<<1024, 256, 0, stream>>>(x, W, b, batch, U, Z, alpha, N);
    nap_finalize<<<512, 256, 0, stream>>>(U, Z, pooled, alpha, G_SEGS * C_CH, N);
}